// Round 4
// baseline (3752.784 us; speedup 1.0000x reference)
//
#include <hip/hip_runtime.h>
#include <stdint.h>
#include <stddef.h>

#define NB 1024
#define TB 1024
#define D_IN 6
#define UNITS 64
#define WIDTH 128
#define DOUT 6
#define EPSF 1e-8f
#define SPB 16          // samples per block (one 16-row MFMA tile)
#define LDK0 104        // c0 row stride (halfs): [0..5]=xn, [6,7]=0, [8..71]=h, [72..95]=0, pad
#define LDK 136         // cP/cQ/cG row stride (halfs); rows 16B-aligned (272 B)

typedef _Float16 v8h __attribute__((ext_vector_type(8)));
typedef float v4f __attribute__((ext_vector_type(4)));

#define MFMAH(A,Bf,C) __builtin_amdgcn_mfma_f32_16x16x32_f16((A),(Bf),(C),0,0,0)

__device__ __forceinline__ float fast_tanh(float v){
  float e = __expf(2.0f * v);
  return 1.0f - __fdividef(2.0f, e + 1.0f);
}

__device__ __forceinline__ void make_frag1(const float* vals, v8h& hv){
  #pragma unroll
  for (int j = 0; j < 8; j++) hv[j] = (_Float16)vals[j];
}
__device__ __forceinline__ void make_frag2(const float* vals, v8h& hv, v8h& lv){
  #pragma unroll
  for (int j = 0; j < 8; j++){
    _Float16 h = (_Float16)vals[j];
    hv[j] = h;
    lv[j] = (_Float16)(vals[j] - (float)h);
  }
}

__global__ __launch_bounds__(256, 1) void lmsc_kernel(
    const float* __restrict__ x, const float* __restrict__ initF,
    const float* __restrict__ w10, const float* __restrict__ b10,
    const float* __restrict__ w20, const float* __restrict__ b20,
    const float* __restrict__ w11, const float* __restrict__ b11,
    const float* __restrict__ w21, const float* __restrict__ b21,
    const float* __restrict__ w12, const float* __restrict__ b12,
    const float* __restrict__ w22, const float* __restrict__ b22,
    const float* __restrict__ wa, const float* __restrict__ ba,
    const float* __restrict__ wb, const float* __restrict__ bb,
    const float* __restrict__ wo,
    float* __restrict__ outs, float* __restrict__ alph)
{
  // ---- LDS: ~21 KB ----
  __shared__ __attribute__((aligned(16))) _Float16 c0[SPB*LDK0];
  __shared__ __attribute__((aligned(16))) _Float16 cP[SPB*LDK];
  __shared__ __attribute__((aligned(16))) _Float16 cQ[SPB*LDK];
  __shared__ __attribute__((aligned(16))) _Float16 cGh[SPB*LDK];
  __shared__ __attribute__((aligned(16))) _Float16 cGl[SPB*LDK];
  __shared__ __attribute__((aligned(16))) float nrm[2][SPB];

  const int tid = threadIdx.x;
  const int wv = tid >> 6;       // wave 0..3
  const int ln = tid & 63;
  const int mn = ln & 15;
  const int qd = ln >> 4;
  const int q8 = qd * 8;
  const int sgbase = (int)blockIdx.x * SPB;
  // column ownership: wave wv owns cols wv*32 .. wv*32+31 (2 tiles)
  const int nb = wv * 32 + mn;   // tile 0 col; tile 1 col = nb + 16

  float tmp[8];

  // ---------------- one-time weight fragments (registers) ----------------
  // L0 [kf][tile][br], K mapped through c0 cols (xn 0..5, h 8..71)
  v8h B0[3][2][2];
  #pragma unroll
  for (int kf = 0; kf < 3; kf++)
    #pragma unroll
    for (int tl = 0; tl < 2; tl++)
      #pragma unroll
      for (int br = 0; br < 2; br++){
        const float* W = br ? w20 : w10;
        int n = nb + tl*16;
        #pragma unroll
        for (int j = 0; j < 8; j++){
          int k = kf*32 + q8 + j;
          int r = (k < 6) ? k : ((k >= 8 && k < 72) ? (k - 2) : -1);
          tmp[j] = (r >= 0) ? W[r*WIDTH + n] : 0.0f;
        }
        make_frag1(tmp, B0[kf][tl][br]);
      }

  // L1, L2
  v8h B1[4][2][2], B2[4][2][2];
  #pragma unroll
  for (int kf = 0; kf < 4; kf++)
    #pragma unroll
    for (int tl = 0; tl < 2; tl++)
      #pragma unroll
      for (int br = 0; br < 2; br++){
        int n = nb + tl*16;
        const float* W = br ? w21 : w11;
        #pragma unroll
        for (int j = 0; j < 8; j++)
          tmp[j] = W[(kf*32 + q8 + j)*WIDTH + n];
        make_frag1(tmp, B1[kf][tl][br]);
        const float* V = br ? w22 : w12;
        #pragma unroll
        for (int j = 0; j < 8; j++)
          tmp[j] = V[(kf*32 + q8 + j)*WIDTH + n];
        make_frag1(tmp, B2[kf][tl][br]);
      }

  // D-phase weights: waves 0,1 own units ub..ub+31. wa hi+lo (alpha), wb single (beta).
  const int ub = wv * 32;
  v8h Bah[4][2], Bal[4][2], Bbh[4][2];
  float bsa[2], bsb[2];
  float hreg[2][4];
  if (wv < 2){
    #pragma unroll
    for (int kf = 0; kf < 4; kf++)
      #pragma unroll
      for (int tl = 0; tl < 2; tl++){
        int u = ub + tl*16 + mn;
        #pragma unroll
        for (int j = 0; j < 8; j++)
          tmp[j] = wa[(kf*32 + q8 + j)*UNITS + u];
        make_frag2(tmp, Bah[kf][tl], Bal[kf][tl]);
        #pragma unroll
        for (int j = 0; j < 8; j++)
          tmp[j] = wb[(kf*32 + q8 + j)*UNITS + u];
        make_frag1(tmp, Bbh[kf][tl]);
      }
    #pragma unroll
    for (int tl = 0; tl < 2; tl++){
      bsa[tl] = ba[ub + tl*16 + mn];
      bsb[tl] = bb[ub + tl*16 + mn];
    }
  }

  // wout on wave 3 (K=64 over h, N=6 padded to 16): hi+lo fp16
  v8h Woh0, Wol0, Woh1, Wol1;
  if (wv == 3){
    #pragma unroll
    for (int j = 0; j < 8; j++)
      tmp[j] = (mn < DOUT) ? wo[(q8 + j)*DOUT + mn] : 0.0f;
    make_frag2(tmp, Woh0, Wol0);
    #pragma unroll
    for (int j = 0; j < 8; j++)
      tmp[j] = (mn < DOUT) ? wo[(32 + q8 + j)*DOUT + mn] : 0.0f;
    make_frag2(tmp, Woh1, Wol1);
  }

  // L0-L2 biases per (tile)
  float bs0a[2], bs0b[2], bs1a[2], bs1b[2], bs2a[2], bs2b[2];
  #pragma unroll
  for (int tl = 0; tl < 2; tl++){
    int n = nb + tl*16;
    bs0a[tl] = b10[n]; bs0b[tl] = b20[n];
    bs1a[tl] = b11[n]; bs1b[tl] = b21[n];
    bs2a[tl] = b12[n]; bs2b[tl] = b22[n];
  }

  // ---------------- init ----------------
  for (int i = tid; i < SPB*LDK0; i += 256) c0[i] = (_Float16)0.0f;
  __syncthreads();

  // h init: waves 0,1 hold h in frag layout (col=unit, row=sample) and seed c0
  if (wv < 2){
    #pragma unroll
    for (int tl = 0; tl < 2; tl++)
      #pragma unroll
      for (int r = 0; r < 4; r++){
        int s = qd*4 + r;
        int u = ub + tl*16 + mn;
        float v = initF[(size_t)(sgbase + s)*(2 + UNITS) + 2 + u];
        hreg[tl][r] = v;
        c0[s*LDK0 + 8 + u] = (_Float16)v;
      }
  }
  float xv0=0, xv1=0, xv2=0, xv3=0, xv4=0, xv5=0;
  if (wv == 2 && ln < 16){
    const float* xp = x + (size_t)(sgbase + ln)*TB*D_IN;
    float a0=xp[0], a1=xp[1], a2=xp[2], a3=xp[3], a4=xp[4], a5=xp[5];
    float nv = sqrtf(a0*a0 + a1*a1 + a2*a2 + a3*a3 + a4*a4 + a5*a5);
    nrm[0][ln] = nv;
    float inv = 1.0f / (nv + EPSF);
    c0[ln*LDK0 + 0] = (_Float16)(a0*inv);
    c0[ln*LDK0 + 1] = (_Float16)(a1*inv);
    c0[ln*LDK0 + 2] = (_Float16)(a2*inv);
    c0[ln*LDK0 + 3] = (_Float16)(a3*inv);
    c0[ln*LDK0 + 4] = (_Float16)(a4*inv);
    c0[ln*LDK0 + 5] = (_Float16)(a5*inv);
    xv0 = xp[6]; xv1 = xp[7]; xv2 = xp[8]; xv3 = xp[9]; xv4 = xp[10]; xv5 = xp[11];  // x(t=1)
  }
  __syncthreads();

  auto wout_phase = [&](int tt){
    v8h ah0 = *(const v8h*)(c0 + mn*LDK0 + 8 + q8);
    v8h ah1 = *(const v8h*)(c0 + mn*LDK0 + 40 + q8);
    v4f acc = {0.f, 0.f, 0.f, 0.f};
    acc = MFMAH(ah0, Woh0, acc); acc = MFMAH(ah0, Wol0, acc);
    acc = MFMAH(ah1, Woh1, acc); acc = MFMAH(ah1, Wol1, acc);
    if (mn < DOUT){
      #pragma unroll
      for (int r = 0; r < 4; r++){
        size_t sg = (size_t)(sgbase + qd*4 + r);
        outs[(sg*TB + (size_t)tt)*DOUT + mn] = acc[r];
      }
    }
  };

  // ================= time loop (4 barriers/step) =================
  for (int t = 0; t < TB; t++){
    // ---- Phase A: L0 (c0 -> cP); wave3 also wout(t-1) ----
    {
      v8h ah[3];
      #pragma unroll
      for (int kf = 0; kf < 3; kf++)
        ah[kf] = *(const v8h*)(c0 + mn*LDK0 + kf*32 + q8);
      v4f acc[2][2];
      #pragma unroll
      for (int tl = 0; tl < 2; tl++){
        acc[tl][0] = (v4f){bs0a[tl], bs0a[tl], bs0a[tl], bs0a[tl]};
        acc[tl][1] = (v4f){bs0b[tl], bs0b[tl], bs0b[tl], bs0b[tl]};
      }
      #pragma unroll
      for (int kf = 0; kf < 3; kf++)
        #pragma unroll
        for (int tl = 0; tl < 2; tl++){
          acc[tl][0] = MFMAH(ah[kf], B0[kf][tl][0], acc[tl][0]);
          acc[tl][1] = MFMAH(ah[kf], B0[kf][tl][1], acc[tl][1]);
        }
      if (wv == 3 && t > 0) wout_phase(t - 1);
      #pragma unroll
      for (int tl = 0; tl < 2; tl++)
        #pragma unroll
        for (int r = 0; r < 4; r++){
          float v = fast_tanh(acc[tl][0][r]) * fast_tanh(acc[tl][1][r]);
          cP[(qd*4 + r)*LDK + nb + tl*16] = (_Float16)v;
        }
    }
    __syncthreads();  // b1

    // ---- Phase B: L1 (cP -> cQ) ----
    {
      v8h ah[4];
      #pragma unroll
      for (int kf = 0; kf < 4; kf++)
        ah[kf] = *(const v8h*)(cP + mn*LDK + kf*32 + q8);
      v4f acc[2][2];
      #pragma unroll
      for (int tl = 0; tl < 2; tl++){
        acc[tl][0] = (v4f){bs1a[tl], bs1a[tl], bs1a[tl], bs1a[tl]};
        acc[tl][1] = (v4f){bs1b[tl], bs1b[tl], bs1b[tl], bs1b[tl]};
      }
      #pragma unroll
      for (int kf = 0; kf < 4; kf++)
        #pragma unroll
        for (int tl = 0; tl < 2; tl++){
          acc[tl][0] = MFMAH(ah[kf], B1[kf][tl][0], acc[tl][0]);
          acc[tl][1] = MFMAH(ah[kf], B1[kf][tl][1], acc[tl][1]);
        }
      #pragma unroll
      for (int tl = 0; tl < 2; tl++)
        #pragma unroll
        for (int r = 0; r < 4; r++){
          float v = fast_tanh(acc[tl][0][r]) * fast_tanh(acc[tl][1][r]);
          cQ[(qd*4 + r)*LDK + nb + tl*16] = (_Float16)v;
        }
    }
    __syncthreads();  // b2

    // ---- Phase C: L2 (cQ -> g hi/lo), g = tanh(x1*x2) ----
    {
      v8h ah[4];
      #pragma unroll
      for (int kf = 0; kf < 4; kf++)
        ah[kf] = *(const v8h*)(cQ + mn*LDK + kf*32 + q8);
      v4f acc[2][2];
      #pragma unroll
      for (int tl = 0; tl < 2; tl++){
        acc[tl][0] = (v4f){bs2a[tl], bs2a[tl], bs2a[tl], bs2a[tl]};
        acc[tl][1] = (v4f){bs2b[tl], bs2b[tl], bs2b[tl], bs2b[tl]};
      }
      #pragma unroll
      for (int kf = 0; kf < 4; kf++)
        #pragma unroll
        for (int tl = 0; tl < 2; tl++){
          acc[tl][0] = MFMAH(ah[kf], B2[kf][tl][0], acc[tl][0]);
          acc[tl][1] = MFMAH(ah[kf], B2[kf][tl][1], acc[tl][1]);
        }
      #pragma unroll
      for (int tl = 0; tl < 2; tl++)
        #pragma unroll
        for (int r = 0; r < 4; r++){
          float v = fast_tanh(acc[tl][0][r] * acc[tl][1][r]);
          int idx = (qd*4 + r)*LDK + nb + tl*16;
          _Float16 hh = (_Float16)v;
          cGh[idx] = hh;
          cGl[idx] = (_Float16)(v - (float)hh);
        }
    }
    __syncthreads();  // b3

    // ---- Phase D: waves 0,1: preA (3-term) + preB (1-term) + h update (regs);
    //               wave 2: x-norm(t+1) ----
    if (wv < 2){
      v8h gh[4], gl[4];
      #pragma unroll
      for (int kf = 0; kf < 4; kf++){
        gh[kf] = *(const v8h*)(cGh + mn*LDK + kf*32 + q8);
        gl[kf] = *(const v8h*)(cGl + mn*LDK + kf*32 + q8);
      }
      v4f pA[2], pB[2];
      #pragma unroll
      for (int tl = 0; tl < 2; tl++){
        pA[tl] = (v4f){bsa[tl], bsa[tl], bsa[tl], bsa[tl]};
        pB[tl] = (v4f){bsb[tl], bsb[tl], bsb[tl], bsb[tl]};
      }
      #pragma unroll
      for (int kf = 0; kf < 4; kf++)
        #pragma unroll
        for (int tl = 0; tl < 2; tl++){
          pA[tl] = MFMAH(gh[kf], Bah[kf][tl], pA[tl]);
          pA[tl] = MFMAH(gl[kf], Bah[kf][tl], pA[tl]);
          pA[tl] = MFMAH(gh[kf], Bal[kf][tl], pA[tl]);
          pB[tl] = MFMAH(gh[kf], Bbh[kf][tl], pB[tl]);
        }
      #pragma unroll
      for (int tl = 0; tl < 2; tl++)
        #pragma unroll
        for (int r = 0; r < 4; r++){
          int s = qd*4 + r;
          int u = ub + tl*16 + mn;
          float nv = nrm[t & 1][s];
          float alpha = __expf(pA[tl][r]);
          float beta  = fast_tanh(pB[tl][r]);
          float dec   = __expf(-alpha * nv);
          float h = dec * (hreg[tl][r] - beta) + beta;
          hreg[tl][r] = h;
          c0[s*LDK0 + 8 + u] = (_Float16)h;
          alph[((size_t)(sgbase + s)*TB + (size_t)t)*UNITS + u] = alpha;
        }
    } else if (wv == 2 && ln < 16){
      float nv2 = sqrtf(xv0*xv0 + xv1*xv1 + xv2*xv2 + xv3*xv3 + xv4*xv4 + xv5*xv5);
      nrm[(t + 1) & 1][ln] = nv2;
      float inv = 1.0f / (nv2 + EPSF);
      c0[ln*LDK0 + 0] = (_Float16)(xv0*inv);
      c0[ln*LDK0 + 1] = (_Float16)(xv1*inv);
      c0[ln*LDK0 + 2] = (_Float16)(xv2*inv);
      c0[ln*LDK0 + 3] = (_Float16)(xv3*inv);
      c0[ln*LDK0 + 4] = (_Float16)(xv4*inv);
      c0[ln*LDK0 + 5] = (_Float16)(xv5*inv);
      int tn = t + 2; if (tn > TB - 1) tn = TB - 1;
      const float* xp = x + ((size_t)(sgbase + ln)*TB + (size_t)tn)*D_IN;
      xv0 = xp[0]; xv1 = xp[1]; xv2 = xp[2]; xv3 = xp[3]; xv4 = xp[4]; xv5 = xp[5];
    }
    __syncthreads();  // b4
  }

  if (wv == 3) wout_phase(TB - 1);
}

extern "C" void kernel_launch(void* const* d_in, const int* in_sizes, int n_in,
                              void* d_out, int out_size, void* d_ws, size_t ws_size,
                              hipStream_t stream) {
  const float* x    = (const float*)d_in[0];
  const float* iF   = (const float*)d_in[1];
  const float* w10  = (const float*)d_in[2];
  const float* b10  = (const float*)d_in[3];
  const float* w20  = (const float*)d_in[4];
  const float* b20  = (const float*)d_in[5];
  const float* w11  = (const float*)d_in[6];
  const float* b11  = (const float*)d_in[7];
  const float* w21  = (const float*)d_in[8];
  const float* b21  = (const float*)d_in[9];
  const float* w12  = (const float*)d_in[10];
  const float* b12  = (const float*)d_in[11];
  const float* w22  = (const float*)d_in[12];
  const float* b22  = (const float*)d_in[13];
  const float* wa   = (const float*)d_in[14];
  const float* ba   = (const float*)d_in[15];
  const float* wb   = (const float*)d_in[16];
  const float* bb   = (const float*)d_in[17];
  const float* wo   = (const float*)d_in[18];

  float* outs = (float*)d_out;
  float* alph = outs + (size_t)NB*TB*DOUT;

  lmsc_kernel<<<NB/SPB, 256, 0, stream>>>(x, iF,
      w10, b10, w20, b20, w11, b11, w21, b21, w12, b12, w22, b22,
      wa, ba, wb, bb, wo, outs, alph);
}

// Round 5
// 3087.945 us; speedup vs baseline: 1.2153x; 1.2153x over previous
//
#include <hip/hip_runtime.h>
#include <stdint.h>
#include <stddef.h>

#define NB 1024
#define TB 1024
#define D_IN 6
#define UNITS 64
#define WIDTH 128
#define DOUT 6
#define EPSF 1e-8f
#define SPB 16          // samples per block (one 16-row MFMA tile)
#define LDK0 108        // c0 row stride (halfs): [0..5]=xn, [6,7]=0, [8..71]=h, [72..95]=0, pad
                        // 108 halfs = 54 dwords == 22 mod 32 -> 16 distinct bank starts (conflict-free)
#define LDK 140         // cP/cQ/cG row stride (halfs): 70 dwords == 6 mod 32 -> conflict-free frag reads

typedef _Float16 v8h __attribute__((ext_vector_type(8)));
typedef float v4f __attribute__((ext_vector_type(4)));

#define MFMAH(A,Bf,C) __builtin_amdgcn_mfma_f32_16x16x32_f16((A),(Bf),(C),0,0,0)

__device__ __forceinline__ float fast_tanh(float v){
  float e = __expf(2.0f * v);
  return 1.0f - __fdividef(2.0f, e + 1.0f);
}
// tanh(a)*tanh(b) with 3 transcendentals: (E1E2 - (E1+E2) + 1)/(E1E2 + (E1+E2) + 1)
__device__ __forceinline__ float tanh_prod(float a, float b){
  a = fminf(fmaxf(a, -18.0f), 18.0f);
  b = fminf(fmaxf(b, -18.0f), 18.0f);
  float E1 = __expf(2.0f * a);
  float E2 = __expf(2.0f * b);
  float P = E1 * E2, S = E1 + E2;
  return (P - S + 1.0f) * __frcp_rn(P + S + 1.0f);
}

__device__ __forceinline__ void make_frag1(const float* vals, v8h& hv){
  #pragma unroll
  for (int j = 0; j < 8; j++) hv[j] = (_Float16)vals[j];
}
__device__ __forceinline__ void make_frag2(const float* vals, v8h& hv, v8h& lv){
  #pragma unroll
  for (int j = 0; j < 8; j++){
    _Float16 h = (_Float16)vals[j];
    hv[j] = h;
    lv[j] = (_Float16)(vals[j] - (float)h);
  }
}

__global__ __launch_bounds__(512, 2) void lmsc_kernel(
    const float* __restrict__ x, const float* __restrict__ initF,
    const float* __restrict__ w10, const float* __restrict__ b10,
    const float* __restrict__ w20, const float* __restrict__ b20,
    const float* __restrict__ w11, const float* __restrict__ b11,
    const float* __restrict__ w21, const float* __restrict__ b21,
    const float* __restrict__ w12, const float* __restrict__ b12,
    const float* __restrict__ w22, const float* __restrict__ b22,
    const float* __restrict__ wa, const float* __restrict__ ba,
    const float* __restrict__ wb, const float* __restrict__ bb,
    const float* __restrict__ wo,
    float* __restrict__ outs, float* __restrict__ alph)
{
  // ---- LDS: ~27 KB ----
  __shared__ __attribute__((aligned(16))) _Float16 c0[2][SPB*LDK0];  // t-parity double buffer
  __shared__ __attribute__((aligned(16))) _Float16 cP[SPB*LDK];
  __shared__ __attribute__((aligned(16))) _Float16 cQ[SPB*LDK];
  __shared__ __attribute__((aligned(16))) _Float16 cGh[SPB*LDK];
  __shared__ __attribute__((aligned(16))) _Float16 cGl[SPB*LDK];
  __shared__ __attribute__((aligned(16))) float nrm[2][SPB];

  const int tid = threadIdx.x;
  const int wv = tid >> 6;       // wave 0..7
  const int ln = tid & 63;
  const int mn = ln & 15;
  const int qd = ln >> 4;
  const int q8 = qd * 8;
  const int n  = wv * 16 + mn;   // col for WIDTH=128 layers (wave owns 16 cols)
  const int sgbase = (int)blockIdx.x * SPB;

  float tmp[8];

  // ---------------- one-time weight fragments (registers) ----------------
  // L0: single fp16; K through c0 cols (xn 0..5, h 8..71), 3 kf
  v8h B0[3][2];
  #pragma unroll
  for (int kf = 0; kf < 3; kf++)
    #pragma unroll
    for (int br = 0; br < 2; br++){
      const float* W = br ? w20 : w10;
      #pragma unroll
      for (int j = 0; j < 8; j++){
        int k = kf*32 + q8 + j;
        int r = (k < 6) ? k : ((k >= 8 && k < 72) ? (k - 2) : -1);
        tmp[j] = (r >= 0) ? W[r*WIDTH + n] : 0.0f;
      }
      make_frag1(tmp, B0[kf][br]);
    }

  // L1, L2: single fp16
  v8h B1[4][2], B2[4][2];
  #pragma unroll
  for (int kf = 0; kf < 4; kf++)
    #pragma unroll
    for (int br = 0; br < 2; br++){
      const float* W = br ? w21 : w11;
      #pragma unroll
      for (int j = 0; j < 8; j++)
        tmp[j] = W[(kf*32 + q8 + j)*WIDTH + n];
      make_frag1(tmp, B1[kf][br]);
      const float* V = br ? w22 : w12;
      #pragma unroll
      for (int j = 0; j < 8; j++)
        tmp[j] = V[(kf*32 + q8 + j)*WIDTH + n];
      make_frag1(tmp, B2[kf][br]);
    }

  // D-phase: wave (wv&3) owns units ub..ub+15; wa hi+lo (alpha path), wb single (beta)
  const int ub = (wv & 3) * 16;
  const int u  = ub + mn;
  v8h Bah[4], Bal[4], Bbh[4];
  #pragma unroll
  for (int kf = 0; kf < 4; kf++){
    #pragma unroll
    for (int j = 0; j < 8; j++)
      tmp[j] = wa[(kf*32 + q8 + j)*UNITS + u];
    make_frag2(tmp, Bah[kf], Bal[kf]);
    #pragma unroll
    for (int j = 0; j < 8; j++)
      tmp[j] = wb[(kf*32 + q8 + j)*UNITS + u];
    make_frag1(tmp, Bbh[kf]);
  }
  const float bsa = ba[u];
  const float bsb = bb[u];

  // wout (K=64 over h, N=6 padded to 16): single fp16 (used by wave 7)
  v8h Woh0, Woh1;
  #pragma unroll
  for (int j = 0; j < 8; j++)
    tmp[j] = (mn < DOUT) ? wo[(q8 + j)*DOUT + mn] : 0.0f;
  make_frag1(tmp, Woh0);
  #pragma unroll
  for (int j = 0; j < 8; j++)
    tmp[j] = (mn < DOUT) ? wo[(32 + q8 + j)*DOUT + mn] : 0.0f;
  make_frag1(tmp, Woh1);

  const float bs0a = b10[n], bs0b = b20[n];
  const float bs1a = b11[n], bs1b = b21[n];
  const float bs2a = b12[n], bs2b = b22[n];

  // ---------------- init ----------------
  for (int i = tid; i < 2*SPB*LDK0; i += 512) c0[0][i] = (_Float16)0.0f;
  __syncthreads();

  // h persistent in registers of waves 0-3 (C-layout: col=unit=u, row=sample=qd*4+r)
  float hreg[4];
  if (wv < 4){
    #pragma unroll
    for (int r = 0; r < 4; r++){
      int s = qd*4 + r;
      float v = initF[(size_t)(sgbase + s)*(2 + UNITS) + 2 + u];
      hreg[r] = v;
      c0[0][s*LDK0 + 8 + u] = (_Float16)v;
    }
  }
  float xv0=0, xv1=0, xv2=0, xv3=0, xv4=0, xv5=0;
  if (wv == 4 && ln < 16){
    const float* xp = x + (size_t)(sgbase + ln)*TB*D_IN;
    float a0=xp[0], a1=xp[1], a2=xp[2], a3=xp[3], a4=xp[4], a5=xp[5];
    float nv = sqrtf(a0*a0 + a1*a1 + a2*a2 + a3*a3 + a4*a4 + a5*a5);
    nrm[0][ln] = nv;
    float inv = 1.0f / (nv + EPSF);
    c0[0][ln*LDK0 + 0] = (_Float16)(a0*inv);
    c0[0][ln*LDK0 + 1] = (_Float16)(a1*inv);
    c0[0][ln*LDK0 + 2] = (_Float16)(a2*inv);
    c0[0][ln*LDK0 + 3] = (_Float16)(a3*inv);
    c0[0][ln*LDK0 + 4] = (_Float16)(a4*inv);
    c0[0][ln*LDK0 + 5] = (_Float16)(a5*inv);
    xv0 = xp[6]; xv1 = xp[7]; xv2 = xp[8]; xv3 = xp[9]; xv4 = xp[10]; xv5 = xp[11];  // x(t=1)
  }
  __syncthreads();

  auto wout_phase = [&](const _Float16* cb, int tt){
    v8h ah0 = *(const v8h*)(cb + mn*LDK0 + 8 + q8);
    v8h ah1 = *(const v8h*)(cb + mn*LDK0 + 40 + q8);
    v4f acc = {0.f, 0.f, 0.f, 0.f};
    acc = MFMAH(ah0, Woh0, acc);
    acc = MFMAH(ah1, Woh1, acc);
    if (mn < DOUT){
      #pragma unroll
      for (int r = 0; r < 4; r++){
        size_t sg = (size_t)(sgbase + qd*4 + r);
        outs[(sg*TB + (size_t)tt)*DOUT + mn] = acc[r];
      }
    }
  };

  // ================= time loop (4 barriers/step) =================
  for (int t = 0; t < TB; t++){
    const int p = t & 1;
    const _Float16* c0r = c0[p];
    _Float16* c0w = c0[p ^ 1];

    // ---- Phase A: L0 (c0[p] -> cP) ----
    {
      v8h ah[3];
      #pragma unroll
      for (int kf = 0; kf < 3; kf++)
        ah[kf] = *(const v8h*)(c0r + mn*LDK0 + kf*32 + q8);
      v4f acc0 = {bs0a, bs0a, bs0a, bs0a};
      v4f acc1 = {bs0b, bs0b, bs0b, bs0b};
      #pragma unroll
      for (int kf = 0; kf < 3; kf++){
        acc0 = MFMAH(ah[kf], B0[kf][0], acc0);
        acc1 = MFMAH(ah[kf], B0[kf][1], acc1);
      }
      #pragma unroll
      for (int r = 0; r < 4; r++)
        cP[(qd*4 + r)*LDK + n] = (_Float16)tanh_prod(acc0[r], acc1[r]);
    }
    __syncthreads();  // b1

    // ---- Phase B: L1 (cP -> cQ) ----
    {
      v8h ah[4];
      #pragma unroll
      for (int kf = 0; kf < 4; kf++)
        ah[kf] = *(const v8h*)(cP + mn*LDK + kf*32 + q8);
      v4f acc0 = {bs1a, bs1a, bs1a, bs1a};
      v4f acc1 = {bs1b, bs1b, bs1b, bs1b};
      #pragma unroll
      for (int kf = 0; kf < 4; kf++){
        acc0 = MFMAH(ah[kf], B1[kf][0], acc0);
        acc1 = MFMAH(ah[kf], B1[kf][1], acc1);
      }
      #pragma unroll
      for (int r = 0; r < 4; r++)
        cQ[(qd*4 + r)*LDK + n] = (_Float16)tanh_prod(acc0[r], acc1[r]);
    }
    __syncthreads();  // b2

    // ---- Phase C: L2 (cQ -> g hi/lo), g = tanh(x1*x2) ----
    {
      v8h ah[4];
      #pragma unroll
      for (int kf = 0; kf < 4; kf++)
        ah[kf] = *(const v8h*)(cQ + mn*LDK + kf*32 + q8);
      v4f acc0 = {bs2a, bs2a, bs2a, bs2a};
      v4f acc1 = {bs2b, bs2b, bs2b, bs2b};
      #pragma unroll
      for (int kf = 0; kf < 4; kf++){
        acc0 = MFMAH(ah[kf], B2[kf][0], acc0);
        acc1 = MFMAH(ah[kf], B2[kf][1], acc1);
      }
      #pragma unroll
      for (int r = 0; r < 4; r++){
        float v = fast_tanh(acc0[r] * acc1[r]);
        int idx = (qd*4 + r)*LDK + n;
        _Float16 hh = (_Float16)v;
        cGh[idx] = hh;
        cGl[idx] = (_Float16)(v - (float)hh);
      }
    }
    __syncthreads();  // b3

    // ---- Phase D:
    //   waves 0-3: pA (3-term, split chains) + pB (1-term) for 16 units; h-update in regs;
    //              write h(t) -> c0[p^1], alpha -> global
    //   wave 7:    wout(t-1) from c0[p]
    //   wave 4:    x-norm(t+1) -> c0[p^1], prefetch x(t+2)
    if (wv < 4){
      v8h gh[4], gl[4];
      #pragma unroll
      for (int kf = 0; kf < 4; kf++){
        gh[kf] = *(const v8h*)(cGh + mn*LDK + kf*32 + q8);
        gl[kf] = *(const v8h*)(cGl + mn*LDK + kf*32 + q8);
      }
      v4f pA0 = {bsa, bsa, bsa, bsa};
      v4f pA1 = {0.f, 0.f, 0.f, 0.f};
      v4f pB  = {bsb, bsb, bsb, bsb};
      // two independent 6-chains for pA + one 4-chain for pB
      #pragma unroll
      for (int kf = 0; kf < 2; kf++){
        pA0 = MFMAH(gh[kf], Bah[kf], pA0);
        pA0 = MFMAH(gl[kf], Bah[kf], pA0);
        pA0 = MFMAH(gh[kf], Bal[kf], pA0);
        pA1 = MFMAH(gh[kf+2], Bah[kf+2], pA1);
        pA1 = MFMAH(gl[kf+2], Bah[kf+2], pA1);
        pA1 = MFMAH(gh[kf+2], Bal[kf+2], pA1);
        pB  = MFMAH(gh[2*kf],   Bbh[2*kf],   pB);
        pB  = MFMAH(gh[2*kf+1], Bbh[2*kf+1], pB);
      }
      #pragma unroll
      for (int r = 0; r < 4; r++){
        int s = qd*4 + r;
        float nv = nrm[p][s];
        float alpha = __expf(pA0[r] + pA1[r]);
        float beta  = fast_tanh(pB[r]);
        float dec   = __expf(-alpha * nv);
        float h = dec * (hreg[r] - beta) + beta;
        hreg[r] = h;
        c0w[s*LDK0 + 8 + u] = (_Float16)h;
        alph[((size_t)(sgbase + s)*TB + (size_t)t)*UNITS + u] = alpha;
      }
    } else if (wv == 7){
      if (t > 0) wout_phase(c0r, t - 1);
    } else if (wv == 4 && ln < 16){
      float nv2 = sqrtf(xv0*xv0 + xv1*xv1 + xv2*xv2 + xv3*xv3 + xv4*xv4 + xv5*xv5);
      nrm[p ^ 1][ln] = nv2;
      float inv = 1.0f / (nv2 + EPSF);
      c0w[ln*LDK0 + 0] = (_Float16)(xv0*inv);
      c0w[ln*LDK0 + 1] = (_Float16)(xv1*inv);
      c0w[ln*LDK0 + 2] = (_Float16)(xv2*inv);
      c0w[ln*LDK0 + 3] = (_Float16)(xv3*inv);
      c0w[ln*LDK0 + 4] = (_Float16)(xv4*inv);
      c0w[ln*LDK0 + 5] = (_Float16)(xv5*inv);
      int tn = t + 2; if (tn > TB - 1) tn = TB - 1;
      const float* xp = x + ((size_t)(sgbase + ln)*TB + (size_t)tn)*D_IN;
      xv0 = xp[0]; xv1 = xp[1]; xv2 = xp[2]; xv3 = xp[3]; xv4 = xp[4]; xv5 = xp[5];
    }
    __syncthreads();  // b4
  }

  // final wout(TB-1): h(TB-1) sits in c0[TB & 1] == c0[0]
  if (wv == 7) wout_phase(c0[TB & 1], TB - 1);
}

extern "C" void kernel_launch(void* const* d_in, const int* in_sizes, int n_in,
                              void* d_out, int out_size, void* d_ws, size_t ws_size,
                              hipStream_t stream) {
  const float* x    = (const float*)d_in[0];
  const float* iF   = (const float*)d_in[1];
  const float* w10  = (const float*)d_in[2];
  const float* b10  = (const float*)d_in[3];
  const float* w20  = (const float*)d_in[4];
  const float* b20  = (const float*)d_in[5];
  const float* w11  = (const float*)d_in[6];
  const float* b11  = (const float*)d_in[7];
  const float* w21  = (const float*)d_in[8];
  const float* b21  = (const float*)d_in[9];
  const float* w12  = (const float*)d_in[10];
  const float* b12  = (const float*)d_in[11];
  const float* w22  = (const float*)d_in[12];
  const float* b22  = (const float*)d_in[13];
  const float* wa   = (const float*)d_in[14];
  const float* ba   = (const float*)d_in[15];
  const float* wb   = (const float*)d_in[16];
  const float* bb   = (const float*)d_in[17];
  const float* wo   = (const float*)d_in[18];

  float* outs = (float*)d_out;
  float* alph = outs + (size_t)NB*TB*DOUT;

  lmsc_kernel<<<NB/SPB, 512, 0, stream>>>(x, iF,
      w10, b10, w20, b20, w11, b11, w21, b21, w12, b12, w22, b22,
      wa, ba, wb, bb, wo, outs, alph);
}

// Round 6
// 2984.341 us; speedup vs baseline: 1.2575x; 1.0347x over previous
//
#include <hip/hip_runtime.h>
#include <stdint.h>
#include <stddef.h>

#define NB 1024
#define TB 1024
#define D_IN 6
#define UNITS 64
#define WIDTH 128
#define DOUT 6
#define EPSF 1e-8f
#define SPB 16          // samples per block (one 16-row MFMA tile)
#define LDK0 108        // c0 row stride (halfs): conflict-free (54 dw == 22 mod 32)
#define LDK 140         // cP/cQ/cG row stride (halfs): conflict-free (70 dw == 6 mod 32)

typedef _Float16 v8h __attribute__((ext_vector_type(8)));
typedef float v4f __attribute__((ext_vector_type(4)));

#define MFMAH(A,Bf,C) __builtin_amdgcn_mfma_f32_16x16x32_f16((A),(Bf),(C),0,0,0)

// LDS-only barrier (composable-kernel idiom): orders LDS across the block but
// does NOT drain vmcnt — global stores/loads stay in flight across it.
#define BARRIER_LDS() asm volatile("s_waitcnt lgkmcnt(0)\n\ts_barrier" ::: "memory")

__device__ __forceinline__ float fast_tanh(float v){
  float e = __expf(2.0f * v);
  return 1.0f - __fdividef(2.0f, e + 1.0f);
}
// tanh(a)*tanh(b) with 3 transcendentals
__device__ __forceinline__ float tanh_prod(float a, float b){
  a = fminf(fmaxf(a, -18.0f), 18.0f);
  b = fminf(fmaxf(b, -18.0f), 18.0f);
  float E1 = __expf(2.0f * a);
  float E2 = __expf(2.0f * b);
  float P = E1 * E2, S = E1 + E2;
  return (P - S + 1.0f) * __frcp_rn(P + S + 1.0f);
}

__device__ __forceinline__ void make_frag1(const float* vals, v8h& hv){
  #pragma unroll
  for (int j = 0; j < 8; j++) hv[j] = (_Float16)vals[j];
}
__device__ __forceinline__ void make_frag2(const float* vals, v8h& hv, v8h& lv){
  #pragma unroll
  for (int j = 0; j < 8; j++){
    _Float16 h = (_Float16)vals[j];
    hv[j] = h;
    lv[j] = (_Float16)(vals[j] - (float)h);
  }
}

__global__ __launch_bounds__(512, 2) void lmsc_kernel(
    const float* __restrict__ x, const float* __restrict__ initF,
    const float* __restrict__ w10, const float* __restrict__ b10,
    const float* __restrict__ w20, const float* __restrict__ b20,
    const float* __restrict__ w11, const float* __restrict__ b11,
    const float* __restrict__ w21, const float* __restrict__ b21,
    const float* __restrict__ w12, const float* __restrict__ b12,
    const float* __restrict__ w22, const float* __restrict__ b22,
    const float* __restrict__ wa, const float* __restrict__ ba,
    const float* __restrict__ wb, const float* __restrict__ bb,
    const float* __restrict__ wo,
    float* __restrict__ outs, float* __restrict__ alph)
{
  // ---- LDS: ~23 KB ----
  __shared__ __attribute__((aligned(16))) _Float16 c0[2][SPB*LDK0];  // t-parity double buffer
  __shared__ __attribute__((aligned(16))) _Float16 cP[SPB*LDK];
  __shared__ __attribute__((aligned(16))) _Float16 cQ[SPB*LDK];
  __shared__ __attribute__((aligned(16))) _Float16 cG[SPB*LDK];
  __shared__ __attribute__((aligned(16))) float nrm[2][SPB];

  const int tid = threadIdx.x;
  const int wv = tid >> 6;       // wave 0..7
  const int ln = tid & 63;
  const int mn = ln & 15;
  const int qd = ln >> 4;
  const int q8 = qd * 8;
  const int n  = wv * 16 + mn;   // col for WIDTH=128 layers (wave owns 16 cols)
  const int sgbase = (int)blockIdx.x * SPB;

  float tmp[8];

  // ---------------- one-time weight fragments (registers) ----------------
  // L0: single fp16; K through c0 cols (xn 0..5, h 8..71), 3 kf
  v8h B0[3][2];
  #pragma unroll
  for (int kf = 0; kf < 3; kf++)
    #pragma unroll
    for (int br = 0; br < 2; br++){
      const float* W = br ? w20 : w10;
      #pragma unroll
      for (int j = 0; j < 8; j++){
        int k = kf*32 + q8 + j;
        int r = (k < 6) ? k : ((k >= 8 && k < 72) ? (k - 2) : -1);
        tmp[j] = (r >= 0) ? W[r*WIDTH + n] : 0.0f;
      }
      make_frag1(tmp, B0[kf][br]);
    }

  // L1, L2: single fp16
  v8h B1[4][2], B2[4][2];
  #pragma unroll
  for (int kf = 0; kf < 4; kf++)
    #pragma unroll
    for (int br = 0; br < 2; br++){
      const float* W = br ? w21 : w11;
      #pragma unroll
      for (int j = 0; j < 8; j++)
        tmp[j] = W[(kf*32 + q8 + j)*WIDTH + n];
      make_frag1(tmp, B1[kf][br]);
      const float* V = br ? w22 : w12;
      #pragma unroll
      for (int j = 0; j < 8; j++)
        tmp[j] = V[(kf*32 + q8 + j)*WIDTH + n];
      make_frag1(tmp, B2[kf][br]);
    }

  // D-phase: wave (wv&3) owns units ub..ub+15; wa hi+lo (alpha path), wb single (beta)
  const int u = (wv & 3) * 16 + mn;
  v8h Bah[4], Bal[4], Bbh[4];
  #pragma unroll
  for (int kf = 0; kf < 4; kf++){
    #pragma unroll
    for (int j = 0; j < 8; j++)
      tmp[j] = wa[(kf*32 + q8 + j)*UNITS + u];
    make_frag2(tmp, Bah[kf], Bal[kf]);
    #pragma unroll
    for (int j = 0; j < 8; j++)
      tmp[j] = wb[(kf*32 + q8 + j)*UNITS + u];
    make_frag1(tmp, Bbh[kf]);
  }
  const float bsa = ba[u];
  const float bsb = bb[u];

  // wout (K=64 over h, N=6 padded to 16): single fp16 (used by wave 7)
  v8h Woh0, Woh1;
  #pragma unroll
  for (int j = 0; j < 8; j++)
    tmp[j] = (mn < DOUT) ? wo[(q8 + j)*DOUT + mn] : 0.0f;
  make_frag1(tmp, Woh0);
  #pragma unroll
  for (int j = 0; j < 8; j++)
    tmp[j] = (mn < DOUT) ? wo[(32 + q8 + j)*DOUT + mn] : 0.0f;
  make_frag1(tmp, Woh1);

  const float bs0a = b10[n], bs0b = b20[n];
  const float bs1a = b11[n], bs1b = b21[n];
  const float bs2a = b12[n], bs2b = b22[n];

  // ---------------- init ----------------
  for (int i = tid; i < 2*SPB*LDK0; i += 512) c0[0][i] = (_Float16)0.0f;
  __syncthreads();

  // h persistent in registers of waves 0-3 (C-layout: col=unit=u, row=sample=qd*4+r)
  float hreg[4];
  if (wv < 4){
    #pragma unroll
    for (int r = 0; r < 4; r++){
      int s = qd*4 + r;
      float v = initF[(size_t)(sgbase + s)*(2 + UNITS) + 2 + u];
      hreg[r] = v;
      c0[0][s*LDK0 + 8 + u] = (_Float16)v;
    }
  }
  float xv0=0, xv1=0, xv2=0, xv3=0, xv4=0, xv5=0;
  if (wv == 4 && ln < 16){
    const float* xp = x + (size_t)(sgbase + ln)*TB*D_IN;
    float a0=xp[0], a1=xp[1], a2=xp[2], a3=xp[3], a4=xp[4], a5=xp[5];
    float nv = sqrtf(a0*a0 + a1*a1 + a2*a2 + a3*a3 + a4*a4 + a5*a5);
    nrm[0][ln] = nv;
    float inv = 1.0f / (nv + EPSF);
    c0[0][ln*LDK0 + 0] = (_Float16)(a0*inv);
    c0[0][ln*LDK0 + 1] = (_Float16)(a1*inv);
    c0[0][ln*LDK0 + 2] = (_Float16)(a2*inv);
    c0[0][ln*LDK0 + 3] = (_Float16)(a3*inv);
    c0[0][ln*LDK0 + 4] = (_Float16)(a4*inv);
    c0[0][ln*LDK0 + 5] = (_Float16)(a5*inv);
    xv0 = xp[6]; xv1 = xp[7]; xv2 = xp[8]; xv3 = xp[9]; xv4 = xp[10]; xv5 = xp[11];  // x(t=1)
  }
  __syncthreads();

  auto wout_phase = [&](const _Float16* cb, int tt){
    v8h ah0 = *(const v8h*)(cb + mn*LDK0 + 8 + q8);
    v8h ah1 = *(const v8h*)(cb + mn*LDK0 + 40 + q8);
    v4f acc = {0.f, 0.f, 0.f, 0.f};
    acc = MFMAH(ah0, Woh0, acc);
    acc = MFMAH(ah1, Woh1, acc);
    if (mn < DOUT){
      #pragma unroll
      for (int r = 0; r < 4; r++){
        size_t sg = (size_t)(sgbase + qd*4 + r);
        outs[(sg*TB + (size_t)tt)*DOUT + mn] = acc[r];
      }
    }
  };

  // ================= time loop (4 LDS-only barriers/step) =================
  for (int t = 0; t < TB; t++){
    const int p = t & 1;
    const _Float16* c0r = c0[p];
    _Float16* c0w = c0[p ^ 1];

    // ---- Phase A: L0 (c0[p] -> cP) ----
    {
      v8h ah[3];
      #pragma unroll
      for (int kf = 0; kf < 3; kf++)
        ah[kf] = *(const v8h*)(c0r + mn*LDK0 + kf*32 + q8);
      v4f acc0 = {bs0a, bs0a, bs0a, bs0a};
      v4f acc1 = {bs0b, bs0b, bs0b, bs0b};
      #pragma unroll
      for (int kf = 0; kf < 3; kf++){
        acc0 = MFMAH(ah[kf], B0[kf][0], acc0);
        acc1 = MFMAH(ah[kf], B0[kf][1], acc1);
      }
      #pragma unroll
      for (int r = 0; r < 4; r++)
        cP[(qd*4 + r)*LDK + n] = (_Float16)tanh_prod(acc0[r], acc1[r]);
    }
    BARRIER_LDS();  // b1

    // ---- Phase B: L1 (cP -> cQ) ----
    {
      v8h ah[4];
      #pragma unroll
      for (int kf = 0; kf < 4; kf++)
        ah[kf] = *(const v8h*)(cP + mn*LDK + kf*32 + q8);
      v4f acc0 = {bs1a, bs1a, bs1a, bs1a};
      v4f acc1 = {bs1b, bs1b, bs1b, bs1b};
      #pragma unroll
      for (int kf = 0; kf < 4; kf++){
        acc0 = MFMAH(ah[kf], B1[kf][0], acc0);
        acc1 = MFMAH(ah[kf], B1[kf][1], acc1);
      }
      #pragma unroll
      for (int r = 0; r < 4; r++)
        cQ[(qd*4 + r)*LDK + n] = (_Float16)tanh_prod(acc0[r], acc1[r]);
    }
    BARRIER_LDS();  // b2

    // ---- Phase C: L2 (cQ -> g), g = tanh(x1*x2) ----
    {
      v8h ah[4];
      #pragma unroll
      for (int kf = 0; kf < 4; kf++)
        ah[kf] = *(const v8h*)(cQ + mn*LDK + kf*32 + q8);
      v4f acc0 = {bs2a, bs2a, bs2a, bs2a};
      v4f acc1 = {bs2b, bs2b, bs2b, bs2b};
      #pragma unroll
      for (int kf = 0; kf < 4; kf++){
        acc0 = MFMAH(ah[kf], B2[kf][0], acc0);
        acc1 = MFMAH(ah[kf], B2[kf][1], acc1);
      }
      #pragma unroll
      for (int r = 0; r < 4; r++)
        cG[(qd*4 + r)*LDK + n] = (_Float16)fast_tanh(acc0[r] * acc1[r]);
    }
    BARRIER_LDS();  // b3

    // ---- Phase D:
    //   waves 0-3: pA (wa hi+lo) + pB for 16 units; h-update in regs;
    //              h(t) -> c0[p^1], alpha -> global (un-drained store)
    //   wave 7:    wout(t-1) from c0[p]
    //   wave 4:    x-norm(t+1) -> c0[p^1], prefetch x(t+2) (latency hidden across steps)
    if (wv < 4){
      v8h gh[4];
      #pragma unroll
      for (int kf = 0; kf < 4; kf++)
        gh[kf] = *(const v8h*)(cG + mn*LDK + kf*32 + q8);
      v4f pA0 = {bsa, bsa, bsa, bsa};
      v4f pA1 = {0.f, 0.f, 0.f, 0.f};
      v4f pB  = {bsb, bsb, bsb, bsb};
      // two independent 4-chains for pA + one 4-chain for pB
      #pragma unroll
      for (int kf = 0; kf < 2; kf++){
        pA0 = MFMAH(gh[kf], Bah[kf], pA0);
        pA0 = MFMAH(gh[kf], Bal[kf], pA0);
        pA1 = MFMAH(gh[kf+2], Bah[kf+2], pA1);
        pA1 = MFMAH(gh[kf+2], Bal[kf+2], pA1);
        pB  = MFMAH(gh[2*kf],   Bbh[2*kf],   pB);
        pB  = MFMAH(gh[2*kf+1], Bbh[2*kf+1], pB);
      }
      #pragma unroll
      for (int r = 0; r < 4; r++){
        int s = qd*4 + r;
        float nv = nrm[p][s];
        float alpha = __expf(pA0[r] + pA1[r]);
        float beta  = fast_tanh(pB[r]);
        float dec   = __expf(-alpha * nv);
        float h = dec * (hreg[r] - beta) + beta;
        hreg[r] = h;
        c0w[s*LDK0 + 8 + u] = (_Float16)h;
        alph[((size_t)(sgbase + s)*TB + (size_t)t)*UNITS + u] = alpha;
      }
    } else if (wv == 7){
      if (t > 0) wout_phase(c0r, t - 1);
    } else if (wv == 4 && ln < 16){
      float nv2 = sqrtf(xv0*xv0 + xv1*xv1 + xv2*xv2 + xv3*xv3 + xv4*xv4 + xv5*xv5);
      nrm[p ^ 1][ln] = nv2;
      float inv = 1.0f / (nv2 + EPSF);
      c0w[ln*LDK0 + 0] = (_Float16)(xv0*inv);
      c0w[ln*LDK0 + 1] = (_Float16)(xv1*inv);
      c0w[ln*LDK0 + 2] = (_Float16)(xv2*inv);
      c0w[ln*LDK0 + 3] = (_Float16)(xv3*inv);
      c0w[ln*LDK0 + 4] = (_Float16)(xv4*inv);
      c0w[ln*LDK0 + 5] = (_Float16)(xv5*inv);
      int tn = t + 2; if (tn > TB - 1) tn = TB - 1;
      const float* xp = x + ((size_t)(sgbase + ln)*TB + (size_t)tn)*D_IN;
      xv0 = xp[0]; xv1 = xp[1]; xv2 = xp[2]; xv3 = xp[3]; xv4 = xp[4]; xv5 = xp[5];
    }
    BARRIER_LDS();  // b4
  }

  // final wout(TB-1): h(TB-1) sits in c0[0]
  if (wv == 7) wout_phase(c0[TB & 1], TB - 1);
}

extern "C" void kernel_launch(void* const* d_in, const int* in_sizes, int n_in,
                              void* d_out, int out_size, void* d_ws, size_t ws_size,
                              hipStream_t stream) {
  const float* x    = (const float*)d_in[0];
  const float* iF   = (const float*)d_in[1];
  const float* w10  = (const float*)d_in[2];
  const float* b10  = (const float*)d_in[3];
  const float* w20  = (const float*)d_in[4];
  const float* b20  = (const float*)d_in[5];
  const float* w11  = (const float*)d_in[6];
  const float* b11  = (const float*)d_in[7];
  const float* w21  = (const float*)d_in[8];
  const float* b21  = (const float*)d_in[9];
  const float* w12  = (const float*)d_in[10];
  const float* b12  = (const float*)d_in[11];
  const float* w22  = (const float*)d_in[12];
  const float* b22  = (const float*)d_in[13];
  const float* wa   = (const float*)d_in[14];
  const float* ba   = (const float*)d_in[15];
  const float* wb   = (const float*)d_in[16];
  const float* bb   = (const float*)d_in[17];
  const float* wo   = (const float*)d_in[18];

  float* outs = (float*)d_out;
  float* alph = outs + (size_t)NB*TB*DOUT;

  lmsc_kernel<<<NB/SPB, 512, 0, stream>>>(x, iF,
      w10, b10, w20, b20, w11, b11, w21, b21, w12, b12, w22, b22,
      wa, ba, wb, bb, wo, outs, alph);
}

// Round 7
// 2692.566 us; speedup vs baseline: 1.3938x; 1.1084x over previous
//
#include <hip/hip_runtime.h>
#include <stdint.h>
#include <stddef.h>

#define NB 1024
#define TB 1024
#define D_IN 6
#define UNITS 64
#define WIDTH 128
#define DOUT 6
#define EPSF 1e-8f
#define SPB 16          // samples per block (one 16-row MFMA tile)
#define LDK0 108        // c0 row stride (halfs): conflict-free (54 dw == 22 mod 32)
#define LDK 140         // cP/cQ/cG row stride (halfs): conflict-free (70 dw == 6 mod 32)

typedef _Float16 v8h __attribute__((ext_vector_type(8)));
typedef float v4f __attribute__((ext_vector_type(4)));

#define MFMAH(A,Bf,C) __builtin_amdgcn_mfma_f32_16x16x32_f16((A),(Bf),(C),0,0,0)

// LDS-only barrier: orders LDS across the block, does NOT drain vmcnt.
#define BARRIER_LDS() asm volatile("s_waitcnt lgkmcnt(0)\n\ts_barrier" ::: "memory")

__device__ __forceinline__ float rcp_fast(float x){ return __builtin_amdgcn_rcpf(x); }

// Pade(7,6) tanh on VALU pipe (1 fast-rcp, no exp). Clamp +-5:
// err < 2e-5 for |x|<4.5, <= ~1e-4 near/beyond clamp.
__device__ __forceinline__ float tanh_r(float x){
  float t = fminf(fmaxf(x, -5.0f), 5.0f);
  float s = t * t;
  float num = t * fmaf(s, fmaf(s, (s + 378.0f), 17325.0f), 135135.0f);
  float den = fmaf(s, fmaf(s, fmaf(s, 28.0f, 3150.0f), 62370.0f), 135135.0f);
  return num * rcp_fast(den);
}

__device__ __forceinline__ void make_frag1(const float* vals, v8h& hv){
  #pragma unroll
  for (int j = 0; j < 8; j++) hv[j] = (_Float16)vals[j];
}
__device__ __forceinline__ void make_frag2(const float* vals, v8h& hv, v8h& lv){
  #pragma unroll
  for (int j = 0; j < 8; j++){
    _Float16 h = (_Float16)vals[j];
    hv[j] = h;
    lv[j] = (_Float16)(vals[j] - (float)h);
  }
}

__global__ __launch_bounds__(512, 2) void lmsc_kernel(
    const float* __restrict__ x, const float* __restrict__ initF,
    const float* __restrict__ w10, const float* __restrict__ b10,
    const float* __restrict__ w20, const float* __restrict__ b20,
    const float* __restrict__ w11, const float* __restrict__ b11,
    const float* __restrict__ w21, const float* __restrict__ b21,
    const float* __restrict__ w12, const float* __restrict__ b12,
    const float* __restrict__ w22, const float* __restrict__ b22,
    const float* __restrict__ wa, const float* __restrict__ ba,
    const float* __restrict__ wb, const float* __restrict__ bb,
    const float* __restrict__ wo,
    float* __restrict__ outs, float* __restrict__ alph)
{
  // ---- LDS: ~20 KB ----
  __shared__ __attribute__((aligned(16))) _Float16 c0[2][SPB*LDK0];  // t-parity double buffer
  __shared__ __attribute__((aligned(16))) _Float16 cP[SPB*LDK];
  __shared__ __attribute__((aligned(16))) _Float16 cQ[SPB*LDK];
  __shared__ __attribute__((aligned(16))) _Float16 cG[SPB*LDK];
  __shared__ __attribute__((aligned(16))) float nrm[2][SPB];

  const int tid = threadIdx.x;
  const int wv = tid >> 6;       // wave 0..7
  const int ln = tid & 63;
  const int mn = ln & 15;
  const int qd = ln >> 4;
  const int q8 = qd * 8;
  const int n  = wv * 16 + mn;   // col for WIDTH=128 layers (wave owns 16 cols)
  const int sgbase = (int)blockIdx.x * SPB;

  float tmp[8];

  // ---------------- one-time weight fragments (registers) ----------------
  // L0: single fp16; K through c0 cols (xn 0..5, h 8..71), 3 kf
  v8h B0[3][2];
  #pragma unroll
  for (int kf = 0; kf < 3; kf++)
    #pragma unroll
    for (int br = 0; br < 2; br++){
      const float* W = br ? w20 : w10;
      #pragma unroll
      for (int j = 0; j < 8; j++){
        int k = kf*32 + q8 + j;
        int r = (k < 6) ? k : ((k >= 8 && k < 72) ? (k - 2) : -1);
        tmp[j] = (r >= 0) ? W[r*WIDTH + n] : 0.0f;
      }
      make_frag1(tmp, B0[kf][br]);
    }

  // L1, L2: single fp16
  v8h B1[4][2], B2[4][2];
  #pragma unroll
  for (int kf = 0; kf < 4; kf++)
    #pragma unroll
    for (int br = 0; br < 2; br++){
      const float* W = br ? w21 : w11;
      #pragma unroll
      for (int j = 0; j < 8; j++)
        tmp[j] = W[(kf*32 + q8 + j)*WIDTH + n];
      make_frag1(tmp, B1[kf][br]);
      const float* V = br ? w22 : w12;
      #pragma unroll
      for (int j = 0; j < 8; j++)
        tmp[j] = V[(kf*32 + q8 + j)*WIDTH + n];
      make_frag1(tmp, B2[kf][br]);
    }

  // D-phase: wave (wv&3) owns units u..u+15; wa hi+lo (alpha path), wb single (beta)
  const int u = (wv & 3) * 16 + mn;
  v8h Bah[4], Bal[4], Bbh[4];
  #pragma unroll
  for (int kf = 0; kf < 4; kf++){
    #pragma unroll
    for (int j = 0; j < 8; j++)
      tmp[j] = wa[(kf*32 + q8 + j)*UNITS + u];
    make_frag2(tmp, Bah[kf], Bal[kf]);
    #pragma unroll
    for (int j = 0; j < 8; j++)
      tmp[j] = wb[(kf*32 + q8 + j)*UNITS + u];
    make_frag1(tmp, Bbh[kf]);
  }
  const float bsa = ba[u];
  const float bsb = bb[u];

  // wout (K=64 over h, N=6 padded to 16): single fp16 (used by wave 7)
  v8h Woh0, Woh1;
  #pragma unroll
  for (int j = 0; j < 8; j++)
    tmp[j] = (mn < DOUT) ? wo[(q8 + j)*DOUT + mn] : 0.0f;
  make_frag1(tmp, Woh0);
  #pragma unroll
  for (int j = 0; j < 8; j++)
    tmp[j] = (mn < DOUT) ? wo[(32 + q8 + j)*DOUT + mn] : 0.0f;
  make_frag1(tmp, Woh1);

  const float bs0a = b10[n], bs0b = b20[n];
  const float bs1a = b11[n], bs1b = b21[n];
  const float bs2a = b12[n], bs2b = b22[n];

  // hoisted global-store bases (loop-invariant 64-bit address math)
  float* alp  = alph + ((size_t)(sgbase + qd*4) * TB) * UNITS + u;          // waves 0-3
  float* outp = outs + ((size_t)(sgbase + qd*4) * TB) * DOUT + mn;          // wave 7

  // ---------------- init ----------------
  for (int i = tid; i < 2*SPB*LDK0; i += 512) c0[0][i] = (_Float16)0.0f;
  __syncthreads();

  // h persistent in registers of waves 0-3 (C-layout: col=unit=u, row=sample=qd*4+r)
  float hreg[4];
  if (wv < 4){
    #pragma unroll
    for (int r = 0; r < 4; r++){
      int s = qd*4 + r;
      float v = initF[(size_t)(sgbase + s)*(2 + UNITS) + 2 + u];
      hreg[r] = v;
      c0[0][s*LDK0 + 8 + u] = (_Float16)v;
    }
  }
  float xv0=0, xv1=0, xv2=0, xv3=0, xv4=0, xv5=0;
  if (wv == 4 && ln < 16){
    const float* xp = x + (size_t)(sgbase + ln)*TB*D_IN;
    float a0=xp[0], a1=xp[1], a2=xp[2], a3=xp[3], a4=xp[4], a5=xp[5];
    float nv = sqrtf(a0*a0 + a1*a1 + a2*a2 + a3*a3 + a4*a4 + a5*a5);
    nrm[0][ln] = nv;
    float inv = 1.0f / (nv + EPSF);
    c0[0][ln*LDK0 + 0] = (_Float16)(a0*inv);
    c0[0][ln*LDK0 + 1] = (_Float16)(a1*inv);
    c0[0][ln*LDK0 + 2] = (_Float16)(a2*inv);
    c0[0][ln*LDK0 + 3] = (_Float16)(a3*inv);
    c0[0][ln*LDK0 + 4] = (_Float16)(a4*inv);
    c0[0][ln*LDK0 + 5] = (_Float16)(a5*inv);
    xv0 = xp[6]; xv1 = xp[7]; xv2 = xp[8]; xv3 = xp[9]; xv4 = xp[10]; xv5 = xp[11];  // x(t=1)
  }
  __syncthreads();

  auto wout_phase = [&](const _Float16* cb, int tt){
    v8h ah0 = *(const v8h*)(cb + mn*LDK0 + 8 + q8);
    v8h ah1 = *(const v8h*)(cb + mn*LDK0 + 40 + q8);
    v4f acc = {0.f, 0.f, 0.f, 0.f};
    acc = MFMAH(ah0, Woh0, acc);
    acc = MFMAH(ah1, Woh1, acc);
    if (mn < DOUT){
      #pragma unroll
      for (int r = 0; r < 4; r++)
        outp[(size_t)r*TB*DOUT + (size_t)tt*DOUT] = acc[r];
    }
  };

  // ================= time loop (4 LDS-only barriers/step) =================
  for (int t = 0; t < TB; t++){
    const int p = t & 1;
    const _Float16* c0r = c0[p];
    _Float16* c0w = c0[p ^ 1];

    // ---- Phase A: L0 (c0[p] -> cP) ----
    {
      v8h ah[3];
      #pragma unroll
      for (int kf = 0; kf < 3; kf++)
        ah[kf] = *(const v8h*)(c0r + mn*LDK0 + kf*32 + q8);
      v4f acc0 = {bs0a, bs0a, bs0a, bs0a};
      v4f acc1 = {bs0b, bs0b, bs0b, bs0b};
      #pragma unroll
      for (int kf = 0; kf < 3; kf++){
        acc0 = MFMAH(ah[kf], B0[kf][0], acc0);
        acc1 = MFMAH(ah[kf], B0[kf][1], acc1);
      }
      #pragma unroll
      for (int r = 0; r < 4; r++)
        cP[(qd*4 + r)*LDK + n] = (_Float16)(tanh_r(acc0[r]) * tanh_r(acc1[r]));
    }
    BARRIER_LDS();  // b1

    // ---- Phase B: L1 (cP -> cQ) ----
    {
      v8h ah[4];
      #pragma unroll
      for (int kf = 0; kf < 4; kf++)
        ah[kf] = *(const v8h*)(cP + mn*LDK + kf*32 + q8);
      v4f acc0 = {bs1a, bs1a, bs1a, bs1a};
      v4f acc1 = {bs1b, bs1b, bs1b, bs1b};
      #pragma unroll
      for (int kf = 0; kf < 4; kf++){
        acc0 = MFMAH(ah[kf], B1[kf][0], acc0);
        acc1 = MFMAH(ah[kf], B1[kf][1], acc1);
      }
      #pragma unroll
      for (int r = 0; r < 4; r++)
        cQ[(qd*4 + r)*LDK + n] = (_Float16)(tanh_r(acc0[r]) * tanh_r(acc1[r]));
    }
    BARRIER_LDS();  // b2

    // ---- Phase C: L2 (cQ -> g), g = tanh(x1*x2) ----
    {
      v8h ah[4];
      #pragma unroll
      for (int kf = 0; kf < 4; kf++)
        ah[kf] = *(const v8h*)(cQ + mn*LDK + kf*32 + q8);
      v4f acc0 = {bs2a, bs2a, bs2a, bs2a};
      v4f acc1 = {bs2b, bs2b, bs2b, bs2b};
      #pragma unroll
      for (int kf = 0; kf < 4; kf++){
        acc0 = MFMAH(ah[kf], B2[kf][0], acc0);
        acc1 = MFMAH(ah[kf], B2[kf][1], acc1);
      }
      #pragma unroll
      for (int r = 0; r < 4; r++)
        cG[(qd*4 + r)*LDK + n] = (_Float16)tanh_r(acc0[r] * acc1[r]);
    }
    BARRIER_LDS();  // b3

    // ---- Phase D:
    //   waves 0-3: pA (wa hi+lo) + pB for 16 units; h-update in regs;
    //              h(t) -> c0[p^1], alpha -> global (un-drained store)
    //   wave 7:    wout(t-1) from c0[p]
    //   wave 4:    x-norm(t+1) -> c0[p^1], prefetch x(t+2)
    if (wv < 4){
      v8h gh[4];
      #pragma unroll
      for (int kf = 0; kf < 4; kf++)
        gh[kf] = *(const v8h*)(cG + mn*LDK + kf*32 + q8);
      v4f pA0 = {bsa, bsa, bsa, bsa};
      v4f pA1 = {0.f, 0.f, 0.f, 0.f};
      v4f pB  = {bsb, bsb, bsb, bsb};
      #pragma unroll
      for (int kf = 0; kf < 2; kf++){
        pA0 = MFMAH(gh[kf], Bah[kf], pA0);
        pA0 = MFMAH(gh[kf], Bal[kf], pA0);
        pA1 = MFMAH(gh[kf+2], Bah[kf+2], pA1);
        pA1 = MFMAH(gh[kf+2], Bal[kf+2], pA1);
        pB  = MFMAH(gh[2*kf],   Bbh[2*kf],   pB);
        pB  = MFMAH(gh[2*kf+1], Bbh[2*kf+1], pB);
      }
      #pragma unroll
      for (int r = 0; r < 4; r++){
        int s = qd*4 + r;
        float nv = nrm[p][s];
        float alpha = __expf(pA0[r] + pA1[r]);
        float beta  = tanh_r(pB[r]);
        float dec   = __expf(-alpha * nv);
        float h = dec * (hreg[r] - beta) + beta;
        hreg[r] = h;
        c0w[s*LDK0 + 8 + u] = (_Float16)h;
        alp[(size_t)r*TB*UNITS + ((size_t)t << 6)] = alpha;
      }
    } else if (wv == 7){
      if (t > 0) wout_phase(c0r, t - 1);
    } else if (wv == 4 && ln < 16){
      float nv2 = sqrtf(xv0*xv0 + xv1*xv1 + xv2*xv2 + xv3*xv3 + xv4*xv4 + xv5*xv5);
      nrm[p ^ 1][ln] = nv2;
      float inv = 1.0f / (nv2 + EPSF);
      c0w[ln*LDK0 + 0] = (_Float16)(xv0*inv);
      c0w[ln*LDK0 + 1] = (_Float16)(xv1*inv);
      c0w[ln*LDK0 + 2] = (_Float16)(xv2*inv);
      c0w[ln*LDK0 + 3] = (_Float16)(xv3*inv);
      c0w[ln*LDK0 + 4] = (_Float16)(xv4*inv);
      c0w[ln*LDK0 + 5] = (_Float16)(xv5*inv);
      int tn = t + 2; if (tn > TB - 1) tn = TB - 1;
      const float* xp = x + ((size_t)(sgbase + ln)*TB + (size_t)tn)*D_IN;
      xv0 = xp[0]; xv1 = xp[1]; xv2 = xp[2]; xv3 = xp[3]; xv4 = xp[4]; xv5 = xp[5];
    }
    BARRIER_LDS();  // b4
  }

  // final wout(TB-1): h(TB-1) sits in c0[0]
  if (wv == 7) wout_phase(c0[TB & 1], TB - 1);
}

extern "C" void kernel_launch(void* const* d_in, const int* in_sizes, int n_in,
                              void* d_out, int out_size, void* d_ws, size_t ws_size,
                              hipStream_t stream) {
  const float* x    = (const float*)d_in[0];
  const float* iF   = (const float*)d_in[1];
  const float* w10  = (const float*)d_in[2];
  const float* b10  = (const float*)d_in[3];
  const float* w20  = (const float*)d_in[4];
  const float* b20  = (const float*)d_in[5];
  const float* w11  = (const float*)d_in[6];
  const float* b11  = (const float*)d_in[7];
  const float* w21  = (const float*)d_in[8];
  const float* b21  = (const float*)d_in[9];
  const float* w12  = (const float*)d_in[10];
  const float* b12  = (const float*)d_in[11];
  const float* w22  = (const float*)d_in[12];
  const float* b22  = (const float*)d_in[13];
  const float* wa   = (const float*)d_in[14];
  const float* ba   = (const float*)d_in[15];
  const float* wb   = (const float*)d_in[16];
  const float* bb   = (const float*)d_in[17];
  const float* wo   = (const float*)d_in[18];

  float* outs = (float*)d_out;
  float* alph = outs + (size_t)NB*TB*DOUT;

  lmsc_kernel<<<NB/SPB, 512, 0, stream>>>(x, iF,
      w10, b10, w20, b20, w11, b11, w21, b21, w12, b12, w22, b22,
      wa, ba, wb, bb, wo, outs, alph);
}